// Round 8
// baseline (402.769 us; speedup 1.0000x reference)
//
#include <hip/hip_runtime.h>
#include <hip/hip_bf16.h>

// ---- problem constants ----
#define LF 4095              // encoder output length: (32768-16)/8 + 1
#define SEQLEN 32768
#define MTOT 16380           // 4*4095 trunk rows, layout [m][256] channels-last
#define NR 44                // mega buffer rows: 32 central + 2*6 halo
#define HALO 6

typedef __attribute__((ext_vector_type(8))) short short8;   // 8 bf16 (4 VGPRs)
typedef __attribute__((ext_vector_type(4))) float f32x4;

__device__ __forceinline__ float bf2f(unsigned short u) {
    return __uint_as_float(((unsigned)u) << 16);
}
__device__ __forceinline__ unsigned short f2bf(float f) {   // round-nearest-even
    unsigned u = __float_as_uint(f);
    return (unsigned short)((u + 0x7FFFu + ((u >> 16) & 1u)) >> 16);
}

// f32 arena element offsets (match host O[] table)
#define dO7  336384   // me_init_b
#define dO8  336640   // blk_ln_g (4x256)
#define dO9  337664   // blk_ln_b
#define dO10 338688   // blk_act_a (4)
#define dO12 535300   // inv_b1 (12x64)
#define dO13 536068   // inv_w2 (12x192)
#define dO14 538372   // inv_b2 (12x3)
#define dO15 538408   // inv_prelu_a (12x256)
#define dO17 803624   // skip_b (4x256)
#define dO19 870184   // me_final_b

// ---------------------------------------------------------------------------
// One-launch prep (unchanged, verified).
// ---------------------------------------------------------------------------
struct PrepArgs { const void* src[28]; long long off[28]; int n[28]; int kind[28]; };

__global__ __launch_bounds__(256) void k_prep(PrepArgs a, float* W, unsigned short* H,
                                              const unsigned* probe) {
    const bool bf = (*probe == 0x3F803F80u);
    const int ph = blockIdx.y;
    const int kind = a.kind[ph];
    const int n = a.n[ph];
    const float* sf = (const float*)a.src[ph];
    const unsigned short* sh = (const unsigned short*)a.src[ph];
    for (int i = blockIdx.x * 256 + threadIdx.x; i < n; i += gridDim.x * 256) {
        const float v = bf ? bf2f(sh[i]) : sf[i];
        if (kind == 0) {
            W[a.off[ph] + i] = v;
        } else if (kind == 1) {
            H[a.off[ph] + i] = bf ? sh[i] : f2bf(v);
        } else {
            const int r = i >> 4, c = i & 15;
            const long long d = a.off[ph] + (long long)c * 256 + r;
            if (kind == 2) W[d] = v;
            else           H[d] = f2bf(v);
        }
    }
}

// ---------------------------------------------------------------------------
// Encoder + fused "me" LayerNorm (unchanged, verified). grid (512,4).
// ---------------------------------------------------------------------------
__global__ __launch_bounds__(256) void k_encoder_ln(
    const float* __restrict__ ac, const float* __restrict__ bc,
    const float* __restrict__ wTa, const float* __restrict__ wTb,
    const float* __restrict__ g, const float* __restrict__ be,
    unsigned short* __restrict__ enc, unsigned short* __restrict__ xout)
{
    __shared__ float E[8][260];
    const int c = threadIdx.x;
    const int b = blockIdx.y;
    const int l0 = blockIdx.x * 8;
    float wa[16], wb[16];
#pragma unroll
    for (int t = 0; t < 16; t++) { wa[t] = wTa[t * 256 + c]; wb[t] = wTb[t * 256 + c]; }
#pragma unroll
    for (int dl = 0; dl < 8; dl++) {
        const int l = l0 + dl;
        float acc = 0.f;
        if (l < LF) {
            const float* pa = ac + (long long)b * SEQLEN + 8 * l;
            const float* pb = bc + (long long)b * SEQLEN + 8 * l;
#pragma unroll
            for (int t = 0; t < 16; t++) acc = fmaf(wa[t], pa[t], fmaf(wb[t], pb[t], acc));
            enc[((long long)b * LF + l) * 256 + c] = f2bf(acc);
        }
        E[dl][c] = acc;
    }
    __syncthreads();
    const int w = threadIdx.x >> 6, lane = threadIdx.x & 63;
    const float4 g4 = *(const float4*)(g + lane * 4);
    const float4 b4 = *(const float4*)(be + lane * 4);
#pragma unroll
    for (int i = 0; i < 2; i++) {
        const int dl = w * 2 + i;
        const int l = l0 + dl;
        if (l >= LF) continue;
        const float4 v = *((const float4*)&E[dl][0] + lane);
        float s  = v.x + v.y + v.z + v.w;
        float ss = fmaf(v.x, v.x, fmaf(v.y, v.y, fmaf(v.z, v.z, v.w * v.w)));
#pragma unroll
        for (int off = 32; off; off >>= 1) { s += __shfl_xor(s, off, 64); ss += __shfl_xor(ss, off, 64); }
        const float mu = s * (1.f / 256.f);
        const float rs = rsqrtf(ss * (1.f / 256.f) - mu * mu + 1e-5f);
        ushort4 o;
        o.x = f2bf(fmaf((v.x - mu) * rs, g4.x, b4.x));
        o.y = f2bf(fmaf((v.y - mu) * rs, g4.y, b4.y));
        o.z = f2bf(fmaf((v.z - mu) * rs, g4.z, b4.z));
        o.w = f2bf(fmaf((v.w - mu) * rs, g4.w, b4.w));
        *(ushort4*)(xout + ((long long)b * LF + l) * 256 + lane * 4) = o;
    }
}

// ---------------------------------------------------------------------------
// Mega phase bodies: __noinline__, ONE copy each, so the whole trunk kernel
// fits the 32 KB I-cache (the inlined version was ~40 KB straight-line code
// and was instruction-fetch bound: ~15k stall cycles per barrier phase).
// 512-thread blocks (8 waves). Buffers [NR][264] bf16; row r <-> g = m0-HALO+r.
// ---------------------------------------------------------------------------

// GEMM, runtime modes (uniform per block): ln = (act_a != nullptr) ->
// prelu+LN epilogue; hasadd = (M3 != nullptr). Wave w owns output cols
// [w*32, w*32+32) (Breg 64 VGPR) and all 3 M-tiles (acc 24 VGPR): <=128 VGPR.
// 3 barriers (ln) / 2 barriers (raw). In-place Obuf==Abuf safe.
__device__ __noinline__ void mega_gemm(
    const unsigned short (*__restrict__ Abuf)[264],
    unsigned short (*__restrict__ Obuf)[264],
    const unsigned short (*__restrict__ M3)[264],
    const unsigned short* __restrict__ Wt,
    const float* __restrict__ bias,
    const float* __restrict__ act_a,
    const float* __restrict__ ln_g, const float* __restrict__ ln_b,
    const int rlo, const int rhi, const int t,
    float (*__restrict__ Part)[16], float (*__restrict__ Ks)[4])
{
    const int w = t >> 6, lane = t & 63;
    const int quad = lane >> 4, l16 = lane & 15;
    const bool ln = (act_a != nullptr);
    const bool hasadd = (M3 != nullptr);

    short8 Breg[8][2];
#pragma unroll
    for (int ks = 0; ks < 8; ks++)
#pragma unroll
        for (int j = 0; j < 2; j++)
            Breg[ks][j] = *(const short8*)&Wt[(w * 32 + j * 16 + l16) * 256 + ks * 32 + quad * 8];

    f32x4 acc[3][2];
#pragma unroll
    for (int i = 0; i < 3; i++)
#pragma unroll
        for (int j = 0; j < 2; j++) acc[i][j] = (f32x4){0.f, 0.f, 0.f, 0.f};

#pragma unroll
    for (int ks = 0; ks < 8; ks++) {
#pragma unroll
        for (int mt = 0; mt < 3; mt++) {
            int ar = mt * 16 + l16; if (ar > NR - 1) ar = NR - 1;
            const short8 af = *(const short8*)&Abuf[ar][ks * 32 + quad * 8];
#pragma unroll
            for (int j = 0; j < 2; j++)
                acc[mt][j] = __builtin_amdgcn_mfma_f32_16x16x32_bf16(af, Breg[ks][j], acc[mt][j], 0, 0, 0);
        }
    }

    float bias2[2], g2[2] = {0.f, 0.f}, b2v[2] = {0.f, 0.f};
    float alpha = 0.f;
#pragma unroll
    for (int j = 0; j < 2; j++) bias2[j] = bias[w * 32 + j * 16 + l16];
    if (ln) {
#pragma unroll
        for (int j = 0; j < 2; j++) {
            g2[j] = ln_g[w * 32 + j * 16 + l16];
            b2v[j] = ln_b[w * 32 + j * 16 + l16];
        }
        alpha = *act_a;
    }

    // epilogue compute: bias [+M3] [+prelu], LN partials per wave (32 cols)
#pragma unroll
    for (int mt = 0; mt < 3; mt++)
#pragma unroll
        for (int r4 = 0; r4 < 4; r4++) {
            const int row = mt * 16 + quad * 4 + r4;
            const int rowc = row < NR ? row : NR - 1;
            float s = 0.f, ss = 0.f;
#pragma unroll
            for (int j = 0; j < 2; j++) {
                float v = acc[mt][j][r4] + bias2[j];
                if (hasadd) v += bf2f(M3[rowc][w * 32 + j * 16 + l16]);
                if (ln) v = v < 0.f ? alpha * v : v;
                acc[mt][j][r4] = v;
                s += v; ss = fmaf(v, v, ss);
            }
            if (ln) {
#pragma unroll
                for (int off = 1; off <= 8; off <<= 1) {
                    s += __shfl_xor(s, off, 64); ss += __shfl_xor(ss, off, 64);
                }
                if (l16 == 0 && row < NR) { Part[row][w] = s; Part[row][8 + w] = ss; }
            }
        }
    __syncthreads();            // Part ready; all Abuf/M3 reads done (in-place safe)
    if (ln) {
        if (t < NR) {
            float s = 0.f, ss = 0.f;
#pragma unroll
            for (int k = 0; k < 8; k++) { s += Part[t][k]; ss += Part[t][8 + k]; }
            const float mu = s * (1.f / 256.f);
            Ks[t][0] = mu;
            Ks[t][1] = rsqrtf(ss * (1.f / 256.f) - mu * mu + 1e-5f);
        }
        __syncthreads();        // Ks ready
    }
    // scatter
#pragma unroll
    for (int mt = 0; mt < 3; mt++)
#pragma unroll
        for (int r4 = 0; r4 < 4; r4++) {
            const int row = mt * 16 + quad * 4 + r4;
            if (row < rlo || row >= rhi) continue;
            float mu = 0.f, rs = 0.f;
            if (ln) { mu = Ks[row][0]; rs = Ks[row][1]; }
#pragma unroll
            for (int j = 0; j < 2; j++) {
                float v = acc[mt][j][r4];
                if (ln) v = fmaf((v - mu) * rs, g2[j], b2v[j]);
                Obuf[row][w * 32 + j * 16 + l16] = f2bf(v);
            }
        }
    __syncthreads();            // Obuf ready
}

// Final mask GEMM: chunked-Cs epilogue (coalesced global write):
// v = relu(A·Wt^T + bias) * enc -> global masked, rows [HALO, NR-HALO).
__device__ __noinline__ void mega_gemm_final(
    const unsigned short (*__restrict__ Abuf)[264],
    float (*__restrict__ Cs)[260],
    const unsigned short* __restrict__ Wt,
    const float* __restrict__ bias,
    const unsigned short* __restrict__ encg,
    unsigned short* __restrict__ maskedg,
    const int m0i, const int t)
{
    const int w = t >> 6, lane = t & 63;
    const int quad = lane >> 4, l16 = lane & 15;

    short8 Breg[8][2];
#pragma unroll
    for (int ks = 0; ks < 8; ks++)
#pragma unroll
        for (int j = 0; j < 2; j++)
            Breg[ks][j] = *(const short8*)&Wt[(w * 32 + j * 16 + l16) * 256 + ks * 32 + quad * 8];

    f32x4 acc[3][2];
#pragma unroll
    for (int i = 0; i < 3; i++)
#pragma unroll
        for (int j = 0; j < 2; j++) acc[i][j] = (f32x4){0.f, 0.f, 0.f, 0.f};

#pragma unroll
    for (int ks = 0; ks < 8; ks++) {
#pragma unroll
        for (int mt = 0; mt < 3; mt++) {
            int ar = mt * 16 + l16; if (ar > NR - 1) ar = NR - 1;
            const short8 af = *(const short8*)&Abuf[ar][ks * 32 + quad * 8];
#pragma unroll
            for (int j = 0; j < 2; j++)
                acc[mt][j] = __builtin_amdgcn_mfma_f32_16x16x32_bf16(af, Breg[ks][j], acc[mt][j], 0, 0, 0);
        }
    }
    const float4 bi4 = *(const float4*)(bias + lane * 4);
    for (int clo = HALO; clo < NR - HALO; clo += 16) {
        const int chi = clo + 16;
        __syncthreads();                     // Cs region free
#pragma unroll
        for (int mt = 0; mt < 3; mt++)
#pragma unroll
            for (int r4 = 0; r4 < 4; r4++) {
                const int row = mt * 16 + quad * 4 + r4;
                if (row >= clo && row < chi) {
#pragma unroll
                    for (int j = 0; j < 2; j++)
                        Cs[row - clo][w * 32 + j * 16 + l16] = acc[mt][j][r4];
                }
            }
        __syncthreads();                     // Cs chunk ready
#pragma unroll
        for (int rr = 0; rr < 2; rr++) {
            const int rl = w * 2 + rr;
            const int row = clo + rl;
            float4 v = *((const float4*)&Cs[rl][0] + lane);
            v.x += bi4.x; v.y += bi4.y; v.z += bi4.z; v.w += bi4.w;
            v.x = fmaxf(v.x, 0.f); v.y = fmaxf(v.y, 0.f);
            v.z = fmaxf(v.z, 0.f); v.w = fmaxf(v.w, 0.f);
            const long long g = (long long)m0i - HALO + row;
            if (g < MTOT) {
                const ushort4 u = *(const ushort4*)(encg + g * 256 + lane * 4);
                v.x *= bf2f(u.x); v.y *= bf2f(u.y); v.z *= bf2f(u.z); v.w *= bf2f(u.w);
                ushort4 o;
                o.x = f2bf(v.x); o.y = f2bf(v.y); o.z = f2bf(v.z); o.w = f2bf(v.w);
                *(ushort4*)(maskedg + g * 256 + lane * 4) = o;
            }
        }
    }
}

// One involution stage, 3 barriers (R5-validated order). 8 waves: wn = w&3
// -> channels [wn*16, wn*16+16); wm = w>>2 -> M-tiles {0,1} / {2}.
// Part layout [r][kk*4+wn]; Ks combine by NR*3 threads.
__device__ __noinline__ void mega_inv(
    const unsigned short (*__restrict__ I)[264],
    unsigned short (*__restrict__ O)[264],
    const unsigned short* __restrict__ W1,
    const float* __restrict__ b1, const float* __restrict__ w2,
    const float* __restrict__ b2, const float* __restrict__ pa,
    const int ilo, const int ihi, const int m0i, const int t,
    float (*__restrict__ Part)[16], float (*__restrict__ Ks)[4])
{
    const int w = t >> 6, lane = t & 63;
    const int quad = lane >> 4, l16 = lane & 15;
    const int wn = w & 3, wm = w >> 2;
    const int o = wn * 16 + l16;             // output channel (0..63)

    short8 W1r[8];
#pragma unroll
    for (int ks = 0; ks < 8; ks++)
        W1r[ks] = *(const short8*)&W1[o * 256 + ks * 32 + quad * 8];

    f32x4 acc[2];
#pragma unroll
    for (int i = 0; i < 2; i++) acc[i] = (f32x4){0.f, 0.f, 0.f, 0.f};
#pragma unroll
    for (int ks = 0; ks < 8; ks++) {
#pragma unroll
        for (int mt = 0; mt < 2; mt++) {
            int ar = (wm * 2 + mt) * 16 + l16; if (ar > NR - 1) ar = NR - 1;
            const short8 af = *(const short8*)&I[ar][ks * 32 + quad * 8];
            acc[mt] = __builtin_amdgcn_mfma_f32_16x16x32_bf16(af, W1r[ks], acc[mt], 0, 0, 0);
        }
    }
    const float b1v = b1[o];
    const float w20 = w2[o], w21 = w2[64 + o], w22 = w2[128 + o];
#pragma unroll
    for (int mt = 0; mt < 2; mt++)
#pragma unroll
        for (int r4 = 0; r4 < 4; r4++) {
            const float c = acc[mt][r4] + b1v;
            float s0 = w20 * c, s1 = w21 * c, s2 = w22 * c;
#pragma unroll
            for (int off = 1; off <= 8; off <<= 1) {
                s0 += __shfl_xor(s0, off, 64);
                s1 += __shfl_xor(s1, off, 64);
                s2 += __shfl_xor(s2, off, 64);
            }
            const int row = (wm * 2 + mt) * 16 + quad * 4 + r4;
            if (l16 < 3 && row < NR)
                Part[row][l16 * 4 + wn] = l16 == 0 ? s0 : (l16 == 1 ? s1 : s2);
        }
    __syncthreads();                         // Part ready
    for (int idx = t; idx < NR * 3; idx += 512) {
        const int r = idx / 3, kk = idx - r * 3;
        Ks[r][kk] = Part[r][kk * 4 + 0] + Part[r][kk * 4 + 1]
                  + Part[r][kk * 4 + 2] + Part[r][kk * 4 + 3] + b2[kk];
    }
    __syncthreads();                         // Ks ready
    for (int r = ilo + 1 + (t >> 3); r < ihi - 1; r += 64) {
        int gc = m0i - HALO + r;
        gc = gc < 0 ? 0 : (gc >= MTOT ? MTOT - 1 : gc);
        const int bb = gc / LF;
        const int l = gc - bb * LF;
        const float k0v = Ks[r][0], k1v = Ks[r][1], k2v = Ks[r][2];
        const bool hasL = (l > 0), hasR = (l < LF - 1);
#pragma unroll
        for (int j = 0; j < 8; j++) {
            const int ch = ((t & 7) + 8 * j) * 4;
            const ushort4 u1 = *(const ushort4*)&I[r][ch];
            const ushort4 u0 = *(const ushort4*)&I[r - 1][ch];
            const ushort4 u2 = *(const ushort4*)&I[r + 1][ch];
            const float4 a4 = *(const float4*)(pa + ch);
            float x0[4] = {hasL ? bf2f(u0.x) : 0.f, hasL ? bf2f(u0.y) : 0.f,
                           hasL ? bf2f(u0.z) : 0.f, hasL ? bf2f(u0.w) : 0.f};
            float x2[4] = {hasR ? bf2f(u2.x) : 0.f, hasR ? bf2f(u2.y) : 0.f,
                           hasR ? bf2f(u2.z) : 0.f, hasR ? bf2f(u2.w) : 0.f};
            const float x1[4] = {bf2f(u1.x), bf2f(u1.y), bf2f(u1.z), bf2f(u1.w)};
            const float aa[4] = {a4.x, a4.y, a4.z, a4.w};
            ushort4 ov;
            unsigned short* op = (unsigned short*)&ov;
#pragma unroll
            for (int i = 0; i < 4; i++) {
                float v = fmaf(k0v, x0[i], fmaf(k1v, x1[i], k2v * x2[i]));
                v = v >= 0.f ? v : aa[i] * v;
                op[i] = f2bf(v);
            }
            *(ushort4*)&O[r][ch] = ov;
        }
    }
    __syncthreads();                         // O ready; Part/Ks reusable
}

// ---------------------------------------------------------------------------
// Mega trunk kernel, two phases (launched twice):
//  phase 0: stage LN0 -> init-GEMM -> chains b=0,1 -> write x2 (global)
//  phase 1: stage x2  -> chains b=2,3 -> final mask -> global masked
// 512 threads (8 waves), 32 central rows, LDS ~71.5 KB -> 2 blocks/CU.
// Phase bodies are __noinline__ (single code copy; fits I-cache). grid 512.
// ---------------------------------------------------------------------------
__global__ __launch_bounds__(512, 2) void k_mega(
    const int phase, const float* __restrict__ W,
    const unsigned short* __restrict__ Hln0,
    const unsigned short* __restrict__ Henc,
    unsigned short* __restrict__ Hx2,
    const unsigned short* __restrict__ Hwinit,
    const unsigned short* __restrict__ Hwskip,
    const unsigned short* __restrict__ Hwfinal,
    const unsigned short* __restrict__ Hwinv,
    unsigned short* __restrict__ Hmasked)
{
    __shared__ __align__(16) unsigned short Buf0[NR][264];   // 23232 B
    __shared__ __align__(16) unsigned short Buf1[NR][264];   // 23232 B
    __shared__ __align__(16) unsigned short Buf2[NR][264];   // 23232 B
    __shared__ float PartU[NR][16];                          //  2816 B (shared gemm/inv)
    __shared__ float KsU[NR][4];                             //   704 B

    const int t = threadIdx.x;
    const int m0i = blockIdx.x * 32;
    const int lr = t >> 3, lcb = (t & 7) * 8;

    // stage input rows [m0-6, m0+38): phase 0 -> Buf0 (LN0); phase 1 -> Buf1 (x2)
    {
        const unsigned short* src = phase == 0 ? Hln0 : Hx2;
        unsigned short (*dst)[264] = phase == 0 ? Buf0 : Buf1;
        for (int r = lr; r < NR; r += 64) {
            int gm = m0i - HALO + r;
            gm = gm < 0 ? 0 : (gm >= MTOT ? MTOT - 1 : gm);
#pragma unroll
            for (int jc = 0; jc < 4; jc++)
                *(float4*)&dst[r][lcb + jc * 64] = *(const float4*)&src[(long long)gm * 256 + lcb + jc * 64];
        }
    }
    __syncthreads();

    if (phase == 0) {
        // me_init GEMM + prelu(a0) + LN(g0,b0): Buf0 -> Buf1 (xn_0)
        mega_gemm(Buf0, Buf1, nullptr,
                  Hwinit, W + dO7, W + dO10 + 0, W + dO8, W + dO9,
                  0, NR, t, PartU, KsU);
    }

    for (int c = 0; c < 2; c++) {
        const int b = phase * 2 + c;
        const int bp = b * 3;
        const int base = 3 * c;
        // inv chain: Buf1 -> Buf2 -> Buf0 -> Buf2 (XN preserved in Buf1)
        mega_inv(Buf1, Buf2, Hwinv + (long long)(bp + 0) * 16384,
                 W + dO12 + (bp + 0) * 64, W + dO13 + (bp + 0) * 192,
                 W + dO14 + (bp + 0) * 3, W + dO15 + (bp + 0) * 256,
                 base, NR - base, m0i, t, PartU, KsU);
        mega_inv(Buf2, Buf0, Hwinv + (long long)(bp + 1) * 16384,
                 W + dO12 + (bp + 1) * 64, W + dO13 + (bp + 1) * 192,
                 W + dO14 + (bp + 1) * 3, W + dO15 + (bp + 1) * 256,
                 base + 1, NR - base - 1, m0i, t, PartU, KsU);
        mega_inv(Buf0, Buf2, Hwinv + (long long)(bp + 2) * 16384,
                 W + dO12 + (bp + 2) * 64, W + dO13 + (bp + 2) * 192,
                 W + dO14 + (bp + 2) * 3, W + dO15 + (bp + 2) * 256,
                 base + 2, NR - base - 2, m0i, t, PartU, KsU);
        // skip GEMM: A=Buf1(xn), M3=Buf2, out=Buf1 in place
        const int slo = base + 3, shi = NR - base - 3;
        if (b < 3) {
            mega_gemm(Buf1, Buf1, Buf2,
                      Hwskip + (long long)b * 65536, W + dO17 + b * 256,
                      W + dO10 + b + 1,
                      W + dO8 + (b + 1) * 256, W + dO9 + (b + 1) * 256,
                      slo, shi, t, PartU, KsU);
        } else {
            mega_gemm(Buf1, Buf1, Buf2,
                      Hwskip + (long long)b * 65536, W + dO17 + b * 256,
                      nullptr, nullptr, nullptr,
                      slo, shi, t, PartU, KsU);
        }
    }

    if (phase == 0) {
        // write x2 central rows [m0, m0+32) to global (coalesced)
        for (int idx = t; idx < 32 * 64; idx += 512) {
            const int r = idx >> 6, c4 = idx & 63;
            const long long g = (long long)m0i + r;
            if (g < MTOT)
                *(ushort4*)(Hx2 + g * 256 + c4 * 4) = *(const ushort4*)&Buf1[HALO + r][c4 * 4];
        }
    } else {
        // masked = enc * relu(me_final(x4)): rows [6,38) -> global; Cs on Buf2
        mega_gemm_final(Buf1, (float(*)[260])Buf2, Hwfinal, W + dO19,
                        Henc, Hmasked, m0i, t);
    }
}

// ---------------------------------------------------------------------------
// Deconv as MFMA GEMM (unchanged, verified).
// ---------------------------------------------------------------------------
__global__ __launch_bounds__(256) void k_deconv(
    const unsigned short* __restrict__ masked, const unsigned short* __restrict__ Wc,
    void* dout, const unsigned* probe)
{
    __shared__ __align__(16) unsigned short As[48][264];  // 25344 B
    __shared__ __align__(16) unsigned short Bs[16][264];  //  8448 B
    __shared__ float Csd[48][20];                         //  3840 B
    const int t = threadIdx.x;
    const int w = t >> 6, lane = t & 63;
    const int quad = lane >> 4, l16 = lane & 15;
    const int g0 = blockIdx.x * 32;
    const int b = g0 >> 12;
    const int lo = g0 & 4095;
    const int lr = t >> 3, lcb = (t & 7) * 8;
    for (int r = lr; r < 48; r += 32) {
        int ml = lo - 1 + r; ml = ml < 0 ? 0 : (ml > LF - 1 ? LF - 1 : ml);
        const long long gm = (long long)b * LF + ml;
#pragma unroll
        for (int jc = 0; jc < 4; jc++)
            *(float4*)&As[r][lcb + jc * 64] = *(const float4*)&masked[gm * 256 + lcb + jc * 64];
    }
    if (lr < 16) {
#pragma unroll
        for (int jc = 0; jc < 4; jc++)
            *(float4*)&Bs[lr][lcb + jc * 64] = *(const float4*)&Wc[(long long)lr * 256 + lcb + jc * 64];
    }
    __syncthreads();
    if (w < 3) {
        f32x4 acc = (f32x4){0.f, 0.f, 0.f, 0.f};
#pragma unroll
        for (int ks = 0; ks < 8; ks++) {
            const short8 af = *(const short8*)&As[w * 16 + l16][ks * 32 + quad * 8];
            const short8 bfr = *(const short8*)&Bs[l16][ks * 32 + quad * 8];
            acc = __builtin_amdgcn_mfma_f32_16x16x32_bf16(af, bfr, acc, 0, 0, 0);
        }
#pragma unroll
        for (int r = 0; r < 4; r++) Csd[w * 16 + quad * 4 + r][l16] = acc[r];
    }
    __syncthreads();
    const int i = t >> 3, j = t & 7;
    const int l0 = lo + i;
    float v = 0.f;
    if (l0 < LF) v = Csd[i + 1][j];
    if (l0 >= 1) v += Csd[i][j + 8];
    const long long oidx = (long long)b * SEQLEN + l0 * 8 + j;
    if (*probe == 0x3F803F80u) ((__hip_bfloat16*)dout)[oidx] = __float2bfloat16(v);
    else                       ((float*)dout)[oidx] = v;
}

// ---------------------------------------------------------------------------
// Host launch (5 launches)
// ---------------------------------------------------------------------------
extern "C" void kernel_launch(void* const* d_in, const int* in_sizes, int n_in,
                              void* d_out, int out_size, void* d_ws, size_t ws_size,
                              hipStream_t stream) {
    float* W = (float*)d_ws;
    const unsigned* probe = (const unsigned*)d_in[4];  // me_ln_g (all ones)

    static const long long O[21] = {
        0, 131072, 262144, 266240, 270336, 270592, 270848, 336384, 336640, 337664,
        338688, 338692, 535300, 536068, 538372, 538408, 541480, 803624, 804648,
        870184, 870440
    };
    const long long ACWT = 874560, BCWT = 878656;
    const long long FEND = 882752;
    unsigned short* H = (unsigned short*)(W + FEND);  // bf16 arena (element offsets)
    const long long WB_INIT  = 0;                     // 65536
    const long long WB_FINAL = 65536;                 // 65536
    const long long WB_SKIP  = 131072;                // 4 x 65536
    const long long WB_INV1  = 393216;                // 12 x 16384
    const long long WB_DEC   = 589824;                // 4096 (Wcat bf16 [16][256])
    const long long B_ENC    = 593920;                // trunk bufs: 16384*256 each
    const long long B_LN0    = B_ENC + 4194304;
    const long long B_X2     = B_LN0 + 4194304;
    const long long B_MASKED = B_X2  + 4194304;

    PrepArgs pa;
    for (int i = 0; i < 21; i++) { pa.src[i] = d_in[i]; pa.off[i] = O[i]; pa.n[i] = in_sizes[i]; pa.kind[i] = 0; }
    pa.src[21] = d_in[6];  pa.off[21] = WB_INIT;  pa.n[21] = 65536;  pa.kind[21] = 1;
    pa.src[22] = d_in[18]; pa.off[22] = WB_FINAL; pa.n[22] = 65536;  pa.kind[22] = 1;
    pa.src[23] = d_in[16]; pa.off[23] = WB_SKIP;  pa.n[23] = 262144; pa.kind[23] = 1;
    pa.src[24] = d_in[11]; pa.off[24] = WB_INV1;  pa.n[24] = 196608; pa.kind[24] = 1;
    pa.src[25] = d_in[2];  pa.off[25] = ACWT;     pa.n[25] = 4096;   pa.kind[25] = 2;
    pa.src[26] = d_in[3];  pa.off[26] = BCWT;     pa.n[26] = 4096;   pa.kind[26] = 2;
    pa.src[27] = d_in[20]; pa.off[27] = WB_DEC;   pa.n[27] = 4096;   pa.kind[27] = 3;
    k_prep<<<dim3(64, 28), 256, 0, stream>>>(pa, W, H, probe);

    // encoder + me-LN: enc(bf16) and LN(enc)(bf16)
    k_encoder_ln<<<dim3(512, 4), 256, 0, stream>>>(W + O[0], W + O[1], W + ACWT, W + BCWT,
                                                   W + O[4], W + O[5], H + B_ENC, H + B_LN0);

    // trunk in two mega launches (noinline phase bodies -> fits I-cache)
    k_mega<<<512, 512, 0, stream>>>(0, W, H + B_LN0, H + B_ENC, H + B_X2,
                                    H + WB_INIT, H + WB_SKIP, H + WB_FINAL,
                                    H + WB_INV1, H + B_MASKED);
    k_mega<<<512, 512, 0, stream>>>(1, W, H + B_LN0, H + B_ENC, H + B_X2,
                                    H + WB_INIT, H + WB_SKIP, H + WB_FINAL,
                                    H + WB_INV1, H + B_MASKED);

    k_deconv<<<512, 256, 0, stream>>>(H + B_MASKED, H + WB_DEC, d_out, probe);
}

// Round 9
// 316.158 us; speedup vs baseline: 1.2739x; 1.2739x over previous
//
#include <hip/hip_runtime.h>
#include <hip/hip_bf16.h>

// ---- problem constants ----
#define LF 4095              // encoder output length: (32768-16)/8 + 1
#define SEQLEN 32768
#define MTOT 16380           // 4*4095 trunk rows, layout [m][256] channels-last

typedef __attribute__((ext_vector_type(8))) short short8;   // 8 bf16 (4 VGPRs)
typedef __attribute__((ext_vector_type(4))) float f32x4;

__device__ __forceinline__ float bf2f(unsigned short u) {
    return __uint_as_float(((unsigned)u) << 16);
}
__device__ __forceinline__ unsigned short f2bf(float f) {   // round-nearest-even
    unsigned u = __float_as_uint(f);
    return (unsigned short)((u + 0x7FFFu + ((u >> 16) & 1u)) >> 16);
}

// f32 arena element offsets (match host O[] table)
#define dO11 338692   // inv_w1 (12x64x256 fp32)
#define dO12 535300   // inv_b1 (12x64)
#define dO13 536068   // inv_w2 (12x192)
#define dO14 538372   // inv_b2 (12x3)

// ---------------------------------------------------------------------------
// One-launch prep. Phases (blockIdx.y), all reading d_in directly:
//  kind 0: convert -> f32 arena        kind 1: cast -> bf16 arena
//  kind 2: transpose [256][16]->[16][256] f32   kind 3: same -> bf16
// dtype probe: me_ln_g all-ones: f32 0x3F800000, bf16 0x3F803F80.
// ---------------------------------------------------------------------------
struct PrepArgs { const void* src[28]; long long off[28]; int n[28]; int kind[28]; };

__global__ __launch_bounds__(256) void k_prep(PrepArgs a, float* W, unsigned short* H,
                                              const unsigned* probe) {
    const bool bf = (*probe == 0x3F803F80u);
    const int ph = blockIdx.y;
    const int kind = a.kind[ph];
    const int n = a.n[ph];
    const float* sf = (const float*)a.src[ph];
    const unsigned short* sh = (const unsigned short*)a.src[ph];
    for (int i = blockIdx.x * 256 + threadIdx.x; i < n; i += gridDim.x * 256) {
        const float v = bf ? bf2f(sh[i]) : sf[i];
        if (kind == 0) {
            W[a.off[ph] + i] = v;
        } else if (kind == 1) {
            H[a.off[ph] + i] = bf ? sh[i] : f2bf(v);
        } else {
            const int r = i >> 4, c = i & 15;
            const long long d = a.off[ph] + (long long)c * 256 + r;
            if (kind == 2) W[d] = v;
            else           H[d] = f2bf(v);
        }
    }
}

// ---------------------------------------------------------------------------
// Effective involution kernels: Weff[bp][k][ch] = sum_o w2[k][o]*W1[o][ch],
// beff[bp][k] = sum_o w2[k][o]*b1[o] + b2[k]. fp32 from the fp32 arena.
// grid 12 x 256 threads.
// ---------------------------------------------------------------------------
__global__ __launch_bounds__(256) void k_weff(const float* __restrict__ W,
                                              float* __restrict__ weff,
                                              float* __restrict__ beff) {
    const int bp = blockIdx.x;
    const int ch = threadIdx.x;
    const float* W1 = W + dO11 + bp * 16384;
    const float* w2 = W + dO13 + bp * 192;
    const float* b1 = W + dO12 + bp * 64;
    const float* b2 = W + dO14 + bp * 3;
#pragma unroll
    for (int k = 0; k < 3; k++) {
        float s = 0.f;
#pragma unroll 8
        for (int o = 0; o < 64; o++) s = fmaf(w2[k * 64 + o], W1[o * 256 + ch], s);
        weff[bp * 768 + k * 256 + ch] = s;
    }
    if (ch < 3) {
        float s = 0.f;
        for (int o = 0; o < 64; o++) s = fmaf(w2[ch * 64 + o], b1[o], s);
        beff[bp * 3 + ch] = s + b2[ch];
    }
}

// ---------------------------------------------------------------------------
// Encoder + fused "me" LayerNorm (R0-verified). grid (512, 4).
// ---------------------------------------------------------------------------
__global__ __launch_bounds__(256) void k_encoder_ln(
    const float* __restrict__ ac, const float* __restrict__ bc,
    const float* __restrict__ wTa, const float* __restrict__ wTb,
    const float* __restrict__ g, const float* __restrict__ be,
    unsigned short* __restrict__ enc, unsigned short* __restrict__ xout)
{
    __shared__ float E[8][260];
    const int c = threadIdx.x;
    const int b = blockIdx.y;
    const int l0 = blockIdx.x * 8;
    float wa[16], wb[16];
#pragma unroll
    for (int t = 0; t < 16; t++) { wa[t] = wTa[t * 256 + c]; wb[t] = wTb[t * 256 + c]; }
#pragma unroll
    for (int dl = 0; dl < 8; dl++) {
        const int l = l0 + dl;
        float acc = 0.f;
        if (l < LF) {
            const float* pa = ac + (long long)b * SEQLEN + 8 * l;
            const float* pb = bc + (long long)b * SEQLEN + 8 * l;
#pragma unroll
            for (int t = 0; t < 16; t++) acc = fmaf(wa[t], pa[t], fmaf(wb[t], pb[t], acc));
            enc[((long long)b * LF + l) * 256 + c] = f2bf(acc);
        }
        E[dl][c] = acc;
    }
    __syncthreads();
    const int w = threadIdx.x >> 6, lane = threadIdx.x & 63;
    const float4 g4 = *(const float4*)(g + lane * 4);
    const float4 b4 = *(const float4*)(be + lane * 4);
#pragma unroll
    for (int i = 0; i < 2; i++) {
        const int dl = w * 2 + i;
        const int l = l0 + dl;
        if (l >= LF) continue;
        const float4 v = *((const float4*)&E[dl][0] + lane);
        float s  = v.x + v.y + v.z + v.w;
        float ss = fmaf(v.x, v.x, fmaf(v.y, v.y, fmaf(v.z, v.z, v.w * v.w)));
#pragma unroll
        for (int off = 32; off; off >>= 1) { s += __shfl_xor(s, off, 64); ss += __shfl_xor(ss, off, 64); }
        const float mu = s * (1.f / 256.f);
        const float rs = rsqrtf(ss * (1.f / 256.f) - mu * mu + 1e-5f);
        ushort4 o;
        o.x = f2bf(fmaf((v.x - mu) * rs, g4.x, b4.x));
        o.y = f2bf(fmaf((v.y - mu) * rs, g4.y, b4.y));
        o.z = f2bf(fmaf((v.z - mu) * rs, g4.z, b4.z));
        o.w = f2bf(fmaf((v.w - mu) * rs, g4.w, b4.w));
        *(ushort4*)(xout + ((long long)b * LF + l) * 256 + lane * 4) = o;
    }
}

// ---------------------------------------------------------------------------
// bf16 MFMA GEMM (R0-verified): M=32/block, N=256, K=256, fused epilogue.
// LDS 41.5 KB (Cs overlays As+Bs) -> 2 blocks/CU at grid 512. In-place safe.
// ---------------------------------------------------------------------------
__global__ __launch_bounds__(256) void k_gemm_fused(
    const unsigned short* __restrict__ A,
    const unsigned short* __restrict__ Wt,
    const float* __restrict__ bias,
    const unsigned short* __restrict__ addsrc,
    const float* __restrict__ act_a,
    const float* __restrict__ ln_g, const float* __restrict__ ln_b,
    const unsigned short* __restrict__ mulsrc, int relu,
    unsigned short* __restrict__ out)
{
    __shared__ __align__(16) char smem[41472];
    unsigned short (*As)[72] = (unsigned short(*)[72])smem;              //  4608 B
    unsigned short (*Bs)[72] = (unsigned short(*)[72])(smem + 4608);     // 36864 B
    float (*Cs)[260] = (float(*)[260])smem;                              // 33280 B overlay
    const int t = threadIdx.x;
    const int w = t >> 6, lane = t & 63;
    const int quad = lane >> 4, l16 = lane & 15;
    const int m0 = blockIdx.x * 32;
    f32x4 acc[2][4];
#pragma unroll
    for (int i = 0; i < 2; i++)
#pragma unroll
        for (int j = 0; j < 4; j++) acc[i][j] = (f32x4){0.f, 0.f, 0.f, 0.f};
    const int lr = t >> 3, lc = (t & 7) * 8;
    for (int k0 = 0; k0 < 256; k0 += 64) {
        __syncthreads();
        {
            long long gm = m0 + lr; if (gm >= MTOT) gm = MTOT - 1;
            *(float4*)&As[lr][lc] = *(const float4*)&A[gm * 256 + k0 + lc];
        }
#pragma unroll
        for (int it = 0; it < 8; it++) {
            const int r = lr + it * 32;
            *(float4*)&Bs[r][lc] = *(const float4*)&Wt[(long long)r * 256 + k0 + lc];
        }
        __syncthreads();
#pragma unroll
        for (int ks = 0; ks < 2; ks++) {
            short8 af[2], bfr[4];
#pragma unroll
            for (int i = 0; i < 2; i++) af[i] = *(const short8*)&As[i * 16 + l16][ks * 32 + quad * 8];
#pragma unroll
            for (int j = 0; j < 4; j++) bfr[j] = *(const short8*)&Bs[w * 64 + j * 16 + l16][ks * 32 + quad * 8];
#pragma unroll
            for (int i = 0; i < 2; i++)
#pragma unroll
                for (int j = 0; j < 4; j++)
                    acc[i][j] = __builtin_amdgcn_mfma_f32_16x16x32_bf16(af[i], bfr[j], acc[i][j], 0, 0, 0);
        }
    }
    __syncthreads();   // As/Bs dead; overlay Cs
#pragma unroll
    for (int i = 0; i < 2; i++)
#pragma unroll
        for (int j = 0; j < 4; j++)
#pragma unroll
            for (int r = 0; r < 4; r++)
                Cs[i * 16 + quad * 4 + r][w * 64 + j * 16 + l16] = acc[i][j][r];
    __syncthreads();
    const float4 bi4 = *(const float4*)(bias + lane * 4);
    float4 g4 = {0.f, 0.f, 0.f, 0.f}, b4 = {0.f, 0.f, 0.f, 0.f};
    if (ln_g) { g4 = *(const float4*)(ln_g + lane * 4); b4 = *(const float4*)(ln_b + lane * 4); }
    const float alpha = act_a ? *act_a : 0.f;
#pragma unroll
    for (int rr = 0; rr < 8; rr++) {
        const int row = w * 8 + rr;
        const int m = m0 + row;
        float4 v = *((const float4*)&Cs[row][0] + lane);
        v.x += bi4.x; v.y += bi4.y; v.z += bi4.z; v.w += bi4.w;
        if (addsrc) {
            const ushort4 u = *(const ushort4*)(addsrc + (long long)m * 256 + lane * 4);
            v.x += bf2f(u.x); v.y += bf2f(u.y); v.z += bf2f(u.z); v.w += bf2f(u.w);
        }
        if (act_a) {
            v.x = v.x < 0.f ? alpha * v.x : v.x;  v.y = v.y < 0.f ? alpha * v.y : v.y;
            v.z = v.z < 0.f ? alpha * v.z : v.z;  v.w = v.w < 0.f ? alpha * v.w : v.w;
        }
        if (ln_g) {
            float s  = v.x + v.y + v.z + v.w;
            float ss = fmaf(v.x, v.x, fmaf(v.y, v.y, fmaf(v.z, v.z, v.w * v.w)));
#pragma unroll
            for (int off = 32; off; off >>= 1) { s += __shfl_xor(s, off, 64); ss += __shfl_xor(ss, off, 64); }
            const float mu = s * (1.f / 256.f);
            const float rs = rsqrtf(ss * (1.f / 256.f) - mu * mu + 1e-5f);
            v.x = fmaf((v.x - mu) * rs, g4.x, b4.x);
            v.y = fmaf((v.y - mu) * rs, g4.y, b4.y);
            v.z = fmaf((v.z - mu) * rs, g4.z, b4.z);
            v.w = fmaf((v.w - mu) * rs, g4.w, b4.w);
        }
        if (relu) {
            v.x = fmaxf(v.x, 0.f); v.y = fmaxf(v.y, 0.f);
            v.z = fmaxf(v.z, 0.f); v.w = fmaxf(v.w, 0.f);
        }
        if (mulsrc) {
            const ushort4 u = *(const ushort4*)(mulsrc + (long long)m * 256 + lane * 4);
            v.x *= bf2f(u.x); v.y *= bf2f(u.y); v.z *= bf2f(u.z); v.w *= bf2f(u.w);
        }
        if (m < MTOT) {
            ushort4 o;
            o.x = f2bf(v.x); o.y = f2bf(v.y); o.z = f2bf(v.z); o.w = f2bf(v.w);
            *(ushort4*)(out + (long long)m * 256 + lane * 4) = o;
        }
    }
}

// ---------------------------------------------------------------------------
// Lite involution: ker = Weff·x + beff (3 length-256 dots/row), then 3-tap
// apply + per-channel PReLU. One wave per row: lane holds 4 channels;
// per-lane partials -> shfl_xor tree; neighbors direct from global (L2-hot).
// No LDS, no barriers, ~40 VGPR -> high occupancy streaming. grid 1024.
// ---------------------------------------------------------------------------
__global__ __launch_bounds__(256) void k_inv_lite(
    const unsigned short* __restrict__ src,
    const float* __restrict__ Weff,     // [3][256]
    const float* __restrict__ beff,     // [3]
    const float* __restrict__ pa,       // [256]
    unsigned short* __restrict__ out)
{
    const int lane = threadIdx.x & 63;
    const int wid = blockIdx.x * 4 + (threadIdx.x >> 6);
    const int nw = gridDim.x * 4;
    const float4 wk0 = *(const float4*)(Weff + lane * 4);
    const float4 wk1 = *(const float4*)(Weff + 256 + lane * 4);
    const float4 wk2 = *(const float4*)(Weff + 512 + lane * 4);
    const float4 a4 = *(const float4*)(pa + lane * 4);
    const float be0 = beff[0], be1 = beff[1], be2 = beff[2];
    const float aa[4] = {a4.x, a4.y, a4.z, a4.w};
    for (int r = wid; r < MTOT; r += nw) {
        const int bb = r / LF;
        const int l = r - bb * LF;
        const long long base = (long long)r * 256 + lane * 4;
        const ushort4 u1 = *(const ushort4*)(src + base);
        const float x1v[4] = {bf2f(u1.x), bf2f(u1.y), bf2f(u1.z), bf2f(u1.w)};
        float p0 = fmaf(wk0.x, x1v[0], fmaf(wk0.y, x1v[1], fmaf(wk0.z, x1v[2], wk0.w * x1v[3])));
        float p1 = fmaf(wk1.x, x1v[0], fmaf(wk1.y, x1v[1], fmaf(wk1.z, x1v[2], wk1.w * x1v[3])));
        float p2 = fmaf(wk2.x, x1v[0], fmaf(wk2.y, x1v[1], fmaf(wk2.z, x1v[2], wk2.w * x1v[3])));
#pragma unroll
        for (int off = 1; off <= 32; off <<= 1) {
            p0 += __shfl_xor(p0, off, 64);
            p1 += __shfl_xor(p1, off, 64);
            p2 += __shfl_xor(p2, off, 64);
        }
        const float k0v = p0 + be0, k1v = p1 + be1, k2v = p2 + be2;
        const bool hasL = (l > 0), hasR = (l < LF - 1);
        float x0v[4] = {0.f, 0.f, 0.f, 0.f}, x2v[4] = {0.f, 0.f, 0.f, 0.f};
        if (hasL) {
            const ushort4 u0 = *(const ushort4*)(src + base - 256);
            x0v[0] = bf2f(u0.x); x0v[1] = bf2f(u0.y); x0v[2] = bf2f(u0.z); x0v[3] = bf2f(u0.w);
        }
        if (hasR) {
            const ushort4 u2 = *(const ushort4*)(src + base + 256);
            x2v[0] = bf2f(u2.x); x2v[1] = bf2f(u2.y); x2v[2] = bf2f(u2.z); x2v[3] = bf2f(u2.w);
        }
        ushort4 o;
        unsigned short* op = (unsigned short*)&o;
#pragma unroll
        for (int i = 0; i < 4; i++) {
            float v = fmaf(k0v, x0v[i], fmaf(k1v, x1v[i], k2v * x2v[i]));
            v = v >= 0.f ? v : aa[i] * v;
            op[i] = f2bf(v);
        }
        *(ushort4*)(out + base) = o;
    }
}

// ---------------------------------------------------------------------------
// Deconv as MFMA GEMM (R0-verified).
// ---------------------------------------------------------------------------
__global__ __launch_bounds__(256) void k_deconv(
    const unsigned short* __restrict__ masked, const unsigned short* __restrict__ Wc,
    void* dout, const unsigned* probe)
{
    __shared__ __align__(16) unsigned short As[48][264];  // 25344 B
    __shared__ __align__(16) unsigned short Bs[16][264];  //  8448 B
    __shared__ float Csd[48][20];                         //  3840 B
    const int t = threadIdx.x;
    const int w = t >> 6, lane = t & 63;
    const int quad = lane >> 4, l16 = lane & 15;
    const int g0 = blockIdx.x * 32;
    const int b = g0 >> 12;
    const int lo = g0 & 4095;
    const int lr = t >> 3, lcb = (t & 7) * 8;
    for (int r = lr; r < 48; r += 32) {
        int ml = lo - 1 + r; ml = ml < 0 ? 0 : (ml > LF - 1 ? LF - 1 : ml);
        const long long gm = (long long)b * LF + ml;
#pragma unroll
        for (int jc = 0; jc < 4; jc++)
            *(float4*)&As[r][lcb + jc * 64] = *(const float4*)&masked[gm * 256 + lcb + jc * 64];
    }
    if (lr < 16) {
#pragma unroll
        for (int jc = 0; jc < 4; jc++)
            *(float4*)&Bs[lr][lcb + jc * 64] = *(const float4*)&Wc[(long long)lr * 256 + lcb + jc * 64];
    }
    __syncthreads();
    if (w < 3) {
        f32x4 acc = (f32x4){0.f, 0.f, 0.f, 0.f};
#pragma unroll
        for (int ks = 0; ks < 8; ks++) {
            const short8 af = *(const short8*)&As[w * 16 + l16][ks * 32 + quad * 8];
            const short8 bfr = *(const short8*)&Bs[l16][ks * 32 + quad * 8];
            acc = __builtin_amdgcn_mfma_f32_16x16x32_bf16(af, bfr, acc, 0, 0, 0);
        }
#pragma unroll
        for (int r = 0; r < 4; r++) Csd[w * 16 + quad * 4 + r][l16] = acc[r];
    }
    __syncthreads();
    const int i = t >> 3, j = t & 7;
    const int l0 = lo + i;
    float v = 0.f;
    if (l0 < LF) v = Csd[i + 1][j];
    if (l0 >= 1) v += Csd[i][j + 8];
    const long long oidx = (long long)b * SEQLEN + l0 * 8 + j;
    if (*probe == 0x3F803F80u) ((__hip_bfloat16*)dout)[oidx] = __float2bfloat16(v);
    else                       ((float*)dout)[oidx] = v;
}

// ---------------------------------------------------------------------------
// Host launch (22 launches)
// ---------------------------------------------------------------------------
extern "C" void kernel_launch(void* const* d_in, const int* in_sizes, int n_in,
                              void* d_out, int out_size, void* d_ws, size_t ws_size,
                              hipStream_t stream) {
    float* W = (float*)d_ws;
    const unsigned* probe = (const unsigned*)d_in[4];  // me_ln_g (all ones)

    static const long long O[21] = {
        0, 131072, 262144, 266240, 270336, 270592, 270848, 336384, 336640, 337664,
        338688, 338692, 535300, 536068, 538372, 538408, 541480, 803624, 804648,
        870184, 870440
    };
    const long long ACWT = 874560, BCWT = 878656;
    const long long WEFF = 882752;                    // 12 x 768 f32
    const long long BEFF = 891968;                    // 12 x 3 f32
    const long long FEND = 892032;
    unsigned short* H = (unsigned short*)(W + FEND);  // bf16 arena (element offsets)
    const long long WB_INIT  = 0;                     // 65536
    const long long WB_FINAL = 65536;                 // 65536
    const long long WB_SKIP  = 131072;                // 4 x 65536
    const long long WB_INV1  = 393216;                // 12 x 16384 (unused now)
    const long long WB_DEC   = 589824;                // 4096 (Wcat bf16 [16][256])
    const long long B_ENC    = 593920;                // trunk bufs: 16384*256 each
    const long long B_LN0    = B_ENC + 4194304;
    const long long B_XN     = B_LN0 + 4194304;
    const long long B_M1     = B_XN  + 4194304;
    const long long B_M2     = B_M1  + 4194304;
    const long long B_MASKED = B_M2  + 4194304;

    PrepArgs pa;
    for (int i = 0; i < 21; i++) { pa.src[i] = d_in[i]; pa.off[i] = O[i]; pa.n[i] = in_sizes[i]; pa.kind[i] = 0; }
    pa.src[21] = d_in[6];  pa.off[21] = WB_INIT;  pa.n[21] = 65536;  pa.kind[21] = 1;
    pa.src[22] = d_in[18]; pa.off[22] = WB_FINAL; pa.n[22] = 65536;  pa.kind[22] = 1;
    pa.src[23] = d_in[16]; pa.off[23] = WB_SKIP;  pa.n[23] = 262144; pa.kind[23] = 1;
    pa.src[24] = d_in[11]; pa.off[24] = WB_INV1;  pa.n[24] = 196608; pa.kind[24] = 1;
    pa.src[25] = d_in[2];  pa.off[25] = ACWT;     pa.n[25] = 4096;   pa.kind[25] = 2;
    pa.src[26] = d_in[3];  pa.off[26] = BCWT;     pa.n[26] = 4096;   pa.kind[26] = 2;
    pa.src[27] = d_in[20]; pa.off[27] = WB_DEC;   pa.n[27] = 4096;   pa.kind[27] = 3;
    k_prep<<<dim3(64, 28), 256, 0, stream>>>(pa, W, H, probe);

    // effective involution kernels (reads fp32 arena written by k_prep)
    k_weff<<<12, 256, 0, stream>>>(W, W + WEFF, W + BEFF);

    // encoder + me-LN: enc(bf16) and LN(enc)(bf16)
    k_encoder_ln<<<dim3(512, 4), 256, 0, stream>>>(W + O[0], W + O[1], W + ACWT, W + BCWT,
                                                   W + O[4], W + O[5], H + B_ENC, H + B_LN0);

    // me_init GEMM + prelu(a0) + LN(g0,b0) -> xn_0
    k_gemm_fused<<<512, 256, 0, stream>>>(H + B_LN0, H + WB_INIT, W + O[7],
                                          nullptr, W + O[10] + 0, W + O[8], W + O[9],
                                          nullptr, 0, H + B_XN);

    for (int b = 0; b < 4; b++) {
        const long long srcs[3] = {B_XN, B_M1, B_M2};
        const long long dsts[3] = {B_M1, B_M2, B_M1};
        for (int p = 0; p < 3; p++) {
            const int bp = b * 3 + p;
            k_inv_lite<<<1024, 256, 0, stream>>>(H + srcs[p],
                                                 W + WEFF + (long long)bp * 768,
                                                 W + BEFF + (long long)bp * 3,
                                                 W + O[15] + bp * 256, H + dsts[p]);
        }
        if (b < 3) {
            k_gemm_fused<<<512, 256, 0, stream>>>(H + B_XN, H + WB_SKIP + (long long)b * 65536,
                                                  W + O[17] + b * 256, H + B_M1,
                                                  W + O[10] + b + 1,
                                                  W + O[8] + (b + 1) * 256, W + O[9] + (b + 1) * 256,
                                                  nullptr, 0, H + B_XN);
        } else {
            k_gemm_fused<<<512, 256, 0, stream>>>(H + B_XN, H + WB_SKIP + (long long)b * 65536,
                                                  W + O[17] + b * 256, H + B_M1,
                                                  nullptr, nullptr, nullptr,
                                                  nullptr, 0, H + B_M2);
        }
    }

    // masked = enc * relu(me_final(x))
    k_gemm_fused<<<512, 256, 0, stream>>>(H + B_M2, H + WB_FINAL, W + O[19],
                                          nullptr, nullptr, nullptr, nullptr,
                                          H + B_ENC, 1, H + B_MASKED);

    k_deconv<<<512, 256, 0, stream>>>(H + B_MASKED, H + WB_DEC, d_out, probe);
}